// Round 1
// baseline (558.695 us; speedup 1.0000x reference)
//
#include <hip/hip_runtime.h>

// ST_Affine: affine_grid (align_corners=False) + grid_sample bilinear/zeros.
// B=16, C=64, H=W=256, fp32 in/out.
//
// V2: h-coarsening (HB=4 rows per thread) + XCD-contiguous block swizzle +
// nontemporal output stores.
//  - Bilinear row overlap between adjacent output rows is now reused
//    *within one thread* (L1-hit) instead of across blocks on different XCDs
//    (HBM re-fetch). Measured fetch was 2.23x input; expect ~1.3x.
//  - Swizzle makes tile-boundary row sharing land in the same XCD's L2.
//  - NT stores keep the 268 MB output stream from evicting input rows in L2.

constexpr int B = 16, C = 64, H = 256, W = 256;
constexpr int HW = H * W;        // 65536
constexpr int CHW = C * HW;      // 4194304
constexpr int HB = 4;            // rows per block / per thread
constexpr int NBLK = B * (H / HB);   // 1024, divisible by 8 (XCDs)

__global__ __launch_bounds__(256) void st_affine_kernel(
    const float* __restrict__ x, const float* __restrict__ theta,
    float* __restrict__ out)
{
    // XCD-contiguous swizzle: XCD k gets blocks [k*chunk, (k+1)*chunk).
    // Hardware round-robins blockIdx across the 8 XCDs; invert that so each
    // XCD processes vertically-contiguous row tiles (L2 row reuse).
    const int bid = blockIdx.x;
    constexpr int CHUNK = NBLK / 8;               // 128
    const int wg = (bid & 7) * CHUNK + (bid >> 3);

    const int b  = wg >> 6;                       // wg / (H/HB), H/HB = 64
    const int h0 = (wg & 63) * HB;
    const int w  = threadIdx.x;                   // lane = w -> coalesced

    // theta[b, 2, 3] row-major flat: [t00 t01 t02 t10 t11 t12] (scalar loads)
    const float* th = theta + b * 6;
    const float t0 = th[0], t1 = th[1], t2 = th[2];
    const float t3 = th[3], t4 = th[4], t5 = th[5];

    const float gx = (w + 0.5f) * (2.0f / W) - 1.0f;

    float wt[HB][4];
    int   off[HB][4];
#pragma unroll
    for (int hh = 0; hh < HB; ++hh) {
        const float gy = (h0 + hh + 0.5f) * (2.0f / H) - 1.0f;

        const float sx = t0 * gx + t1 * gy + t2;
        const float sy = t3 * gx + t4 * gy + t5;

        const float ix = ((sx + 1.0f) * (float)W - 1.0f) * 0.5f;
        const float iy = ((sy + 1.0f) * (float)H - 1.0f) * 0.5f;

        const float ix0f = floorf(ix);
        const float iy0f = floorf(iy);
        const float tx = ix - ix0f;
        const float ty = iy - iy0f;
        const int ix0 = (int)ix0f, iy0 = (int)iy0f;
        const int ix1 = ix0 + 1,   iy1 = iy0 + 1;

        const float vx0 = (ix0 >= 0 && ix0 < W) ? 1.0f : 0.0f;
        const float vx1 = (ix1 >= 0 && ix1 < W) ? 1.0f : 0.0f;
        const float vy0 = (iy0 >= 0 && iy0 < H) ? 1.0f : 0.0f;
        const float vy1 = (iy1 >= 0 && iy1 < H) ? 1.0f : 0.0f;

        wt[hh][0] = (1.0f - tx) * (1.0f - ty) * vx0 * vy0;
        wt[hh][1] = tx          * (1.0f - ty) * vx1 * vy0;
        wt[hh][2] = (1.0f - tx) * ty          * vx0 * vy1;
        wt[hh][3] = tx          * ty          * vx1 * vy1;

        const int cx0 = min(max(ix0, 0), W - 1);
        const int cx1 = min(max(ix1, 0), W - 1);
        const int cy0 = min(max(iy0, 0), H - 1);
        const int cy1 = min(max(iy1, 0), H - 1);

        off[hh][0] = cy0 * W + cx0;
        off[hh][1] = cy0 * W + cx1;
        off[hh][2] = cy1 * W + cx0;
        off[hh][3] = cy1 * W + cx1;
    }

    const float* __restrict__ xb = x + (size_t)b * CHW;
    float* __restrict__ ob = out + (size_t)b * CHW + h0 * W + w;

#pragma unroll 2
    for (int c = 0; c < C; ++c) {
        const float* __restrict__ xc = xb + c * HW;
        float* __restrict__ oc = ob + (size_t)c * HW;
#pragma unroll
        for (int hh = 0; hh < HB; ++hh) {
            const float v = xc[off[hh][0]] * wt[hh][0]
                          + xc[off[hh][1]] * wt[hh][1]
                          + xc[off[hh][2]] * wt[hh][2]
                          + xc[off[hh][3]] * wt[hh][3];
            // output is never re-read: bypass L2 allocation
            __builtin_nontemporal_store(v, oc + hh * W);
        }
    }
}

extern "C" void kernel_launch(void* const* d_in, const int* in_sizes, int n_in,
                              void* d_out, int out_size, void* d_ws, size_t ws_size,
                              hipStream_t stream) {
    const float* x     = (const float*)d_in[0];
    const float* theta = (const float*)d_in[1];
    float* out = (float*)d_out;

    dim3 grid(NBLK), block(256);
    st_affine_kernel<<<grid, block, 0, stream>>>(x, theta, out);
}